// Round 12
// baseline (736.788 us; speedup 1.0000x reference)
//
#include <hip/hip_runtime.h>
#include <math.h>

#define M_TOTAL 32768   // 8 * 4096
#define C_DIM   512
#define K_VOCAB 8192
#define CK      1024    // 2*C_DIM: [hi | mid] bf16 split
#define MOM     0.995f
#define BETA    0.25f

typedef unsigned short u16;
typedef unsigned long long u64;
typedef short bf16x8 __attribute__((ext_vector_type(8)));
typedef float f32x4  __attribute__((ext_vector_type(4)));

// ---- helpers -------------------------------------------------------------
__device__ __forceinline__ u16 f2bf_rn(float f) {
    unsigned u = __float_as_uint(f);
    u += 0x7fffu + ((u >> 16) & 1u);
    return (u16)(u >> 16);
}
__device__ __forceinline__ float bf2f(u16 h) { return __uint_as_float(((unsigned)h) << 16); }
__device__ __forceinline__ void split2(float v, u16& h0, u16& h1) {
    h0 = f2bf_rn(v);
    h1 = f2bf_rn(v - bf2f(h0));
}
__device__ __forceinline__ unsigned fkey(float f) {
    unsigned u = __float_as_uint(f);
    return (u & 0x80000000u) ? ~u : (u | 0x80000000u);
}

// ---------------- prep E ---------------------------------------------------
__global__ __launch_bounds__(256) void vq_prep_e(const float* __restrict__ dict,
                                                 const float* __restrict__ counts,
                                                 float* __restrict__ en2,
                                                 float* __restrict__ rcnt,
                                                 float* __restrict__ new_dict,
                                                 float* __restrict__ new_counts,
                                                 u16* __restrict__ E2) {
    const int k = blockIdx.x;
    const int t = threadIdx.x;
    __shared__ float rc_sh;
    __shared__ float wsum[4];
    if (t == 0) {
        float c = counts[k];
        float rc = 1.0f / c;
        rc_sh = rc; rcnt[k] = rc; new_counts[k] = c * MOM;
    }
    __syncthreads();
    const float rc = rc_sh;
    const float* dr = dict + (size_t)k * C_DIM;
    float* ndr = new_dict + (size_t)k * C_DIM;
    u16* er = E2 + (size_t)k * CK;
    float s = 0.f;
    #pragma unroll
    for (int h = 0; h < 2; ++h) {
        const int c = t + h * 256;
        const float d = dr[c];
        ndr[c] = d * MOM;
        const float e = d * rc;
        s += e * e;
        u16 h0, h1; split2(e, h0, h1);
        er[c] = h0; er[512 + c] = h1;
    }
    #pragma unroll
    for (int off = 32; off > 0; off >>= 1) s += __shfl_down(s, off);
    if ((t & 63) == 0) wsum[t >> 6] = s;
    __syncthreads();
    if (t == 0) en2[k] = wsum[0] + wsum[1] + wsum[2] + wsum[3];
}

// ---------------- prep X ---------------------------------------------------
__global__ __launch_bounds__(256) void vq_prep_x(const float* __restrict__ x,
                                                 u16* __restrict__ X2) {
    const int total = M_TOTAL * C_DIM / 4;
    for (int i = blockIdx.x * 256 + threadIdx.x; i < total; i += gridDim.x * 256) {
        const float4 v = ((const float4*)x)[i];
        const int m = i >> 7;
        const int c4 = (i & 127) << 2;
        u16* base = X2 + (size_t)m * CK + c4;
        ushort4 a, b;
        split2(v.x, a.x, b.x); split2(v.y, a.y, b.y);
        split2(v.z, a.z, b.z); split2(v.w, a.w, b.w);
        *(ushort4*)(base)       = a;
        *(ushort4*)(base + 512) = b;
    }
}

// ---------------- main: 128x128 tile, 2 blocks/CU, XCD-pinned k-split ------
// R11's verified schedule (whole-tile ping-pong staging, race-free; BK=64
// conflict-free XOR swizzle; one vmcnt(0)+barrier per K-tile) + kz=4 split
// pinned to XCD pairs (kz = (blockIdx%8)>>1): each XCD re-reads the SAME
// 4MB E2 slice -> L2-resident, killing R11's 2.16GB L2-miss traffic.
#define STAGE(par, gA, gB)                                                     \
    { _Pragma("unroll")                                                        \
      for (int q_ = 0; q_ < 4; ++q_) {                                         \
        __builtin_amdgcn_global_load_lds(                                      \
            (const __attribute__((address_space(1))) void*)(aB[q_] + (gA)),    \
            (__attribute__((address_space(3))) void*)                          \
                &lds[(par) * 16384 + (q_ * 256 + t) * 8], 16, 0, 0);           \
      }                                                                        \
      _Pragma("unroll")                                                        \
      for (int q_ = 0; q_ < 4; ++q_) {                                         \
        __builtin_amdgcn_global_load_lds(                                      \
            (const __attribute__((address_space(1))) void*)(bB[q_] + (gB)),    \
            (__attribute__((address_space(3))) void*)                          \
                &lds[(par) * 16384 + 8192 + (q_ * 256 + t) * 8], 16, 0, 0);    \
      } }

#define TILE(par)                                                              \
    {                                                                          \
        const size_t gA = (size_t)kc1 * 64;                                    \
        const size_t gB = (size_t)ct1 * (size_t)(128 * CK) + (size_t)kc1 * 64; \
        STAGE((par) ^ 1, gA, gB)                                               \
        bf16x8 af[4][2];                                                       \
        _Pragma("unroll") for (int mf = 0; mf < 4; ++mf)                       \
            _Pragma("unroll") for (int kk = 0; kk < 2; ++kk) {                 \
                const int row_ = arow[mf];                                     \
                af[mf][kk] = *(const bf16x8*)&lds[(par) * 16384 + row_ * 64 +  \
                               (((kk * 4 + l4) ^ (row_ & 7)) * 8)];            \
            }                                                                  \
        bf16x8 bfr[4][2];                                                      \
        _Pragma("unroll") for (int g = 0; g < 4; ++g)                          \
            _Pragma("unroll") for (int kk = 0; kk < 2; ++kk) {                 \
                const int row_ = brow[g];                                      \
                bfr[g][kk] = *(const bf16x8*)&lds[(par) * 16384 + 8192 +       \
                               row_ * 64 + (((kk * 4 + l4) ^ (row_ & 7)) * 8)];\
            }                                                                  \
        __builtin_amdgcn_s_setprio(1);                                         \
        _Pragma("unroll") for (int kk = 0; kk < 2; ++kk)                       \
            _Pragma("unroll") for (int mf = 0; mf < 4; ++mf)                   \
                _Pragma("unroll") for (int g = 0; g < 4; ++g)                  \
                    acc[mf][g] = __builtin_amdgcn_mfma_f32_16x16x32_bf16(      \
                        af[mf][kk], bfr[g][kk], acc[mf][g], 0, 0, 0);          \
        __builtin_amdgcn_s_setprio(0);                                         \
        asm volatile("s_waitcnt vmcnt(0) lgkmcnt(0)" ::: "memory");            \
        if (++kc1 == 16) { kc1 = 0; ct1 = (ct1 + 1) & 15; }                    \
        asm volatile("s_barrier" ::: "memory");                                \
    }

__global__ __launch_bounds__(256, 2) void vq_gemm8(const u16* __restrict__ X2,
                                                   const u16* __restrict__ E2,
                                                   const float* __restrict__ en2,
                                                   u64* __restrict__ part_keys) {
    __shared__ __align__(16) u16 lds[32768];      // 64 KB: 2 bufs x (A 16KB | B 16KB)
    __shared__ u64 keys_lds[2][128];

    const int t = threadIdx.x;
    const int lane = t & 63;
    const int wid = t >> 6;
    const int wm = wid >> 1, wn = wid & 1;        // 2M x 2N wave grid
    const int l15 = lane & 15, l4 = lane >> 4;

    // XCD-pinned k-split: xcd = bid%8 (dispatch round-robin heuristic);
    // kz = xcd>>1 so each XCD pair owns one 2048-code (4MB) E2 slice.
    const int bid = blockIdx.x;                   // grid = 1024
    const int xcd = bid & 7;
    const int kz = xcd >> 1;
    const int mt = ((bid >> 3) << 1) | (xcd & 1); // 0..255, full cover per kz
    const size_t m0 = (size_t)mt * 128;
    const int kbase = kz * 2048;

    // staging: chunk ci = q*256+t -> row ci>>3, slot ci&7 (8 x 16B per 128B row);
    // linear LDS dest + inverse-swizzled global source (both-sides swizzle)
    const u16* aB[4]; const u16* bB[4];
    #pragma unroll
    for (int q = 0; q < 4; ++q) {
        const int ci = q * 256 + t;
        const int row = ci >> 3;
        const int sx = ((ci & 7) ^ (row & 7)) * 8;
        aB[q] = X2 + (m0 + row) * CK + sx;
        bB[q] = E2 + ((size_t)(kbase + row)) * CK + sx;
    }
    int arow[4], brow[4];
    #pragma unroll
    for (int mf = 0; mf < 4; ++mf) arow[mf] = wm * 64 + mf * 16 + l15;
    #pragma unroll
    for (int g = 0; g < 4; ++g) brow[g] = wn * 64 + g * 16 + l15;

    f32x4 acc[4][4];
    u64 keys[16];
    #pragma unroll
    for (int s = 0; s < 16; ++s) keys[s] = ~0ull;

    // prologue: stage tile 0 into buf0
    STAGE(0, 0, 0)
    asm volatile("s_waitcnt vmcnt(0) lgkmcnt(0)" ::: "memory");
    asm volatile("s_barrier" ::: "memory");

    int kc1 = 1, ct1 = 0;   // coords of next tile to stage

    for (int ct = 0; ct < 16; ++ct) {             // 16 code-tiles of 128 (2048/kz)
        const f32x4 z4 = {0.f, 0.f, 0.f, 0.f};
        #pragma unroll
        for (int i = 0; i < 4; ++i)
            #pragma unroll
            for (int j = 0; j < 4; ++j) acc[i][j] = z4;

        #pragma unroll 1
        for (int kp = 0; kp < 8; ++kp) {          // 16 K-tiles per code-tile
            TILE(0)
            TILE(1)
        }
        // fused score + running argmin (en2 direct from global, L2-hot)
        #pragma unroll
        for (int jn = 0; jn < 4; ++jn) {
            const int cl = ct * 128 + wn * 64 + jn * 16 + l15;
            const float e2 = en2[kbase + cl];
            const unsigned cid = (unsigned)(kbase + cl);
            #pragma unroll
            for (int im = 0; im < 4; ++im)
                #pragma unroll
                for (int r = 0; r < 4; ++r) {
                    const float sc = fmaf(-2.0f, acc[im][jn][r], e2);
                    const u64 k = (((u64)fkey(sc)) << 32) | cid;
                    if (k < keys[im * 4 + r]) keys[im * 4 + r] = k;
                }
        }
    }

    asm volatile("s_waitcnt vmcnt(0)" ::: "memory");
    // in-wave reduce across the 16 lanes (codes) of each row group
    #pragma unroll
    for (int s = 0; s < 16; ++s)
        #pragma unroll
        for (int mm = 1; mm < 16; mm <<= 1) {
            const u64 o = __shfl_xor(keys[s], mm);
            if (o < keys[s]) keys[s] = o;
        }
    if (l15 == 0) {
        #pragma unroll
        for (int im = 0; im < 4; ++im)
            #pragma unroll
            for (int r = 0; r < 4; ++r)
                keys_lds[wn][wm * 64 + im * 16 + l4 * 4 + r] = keys[im * 4 + r];
    }
    __syncthreads();
    if (t < 128) {
        const u64 a = keys_lds[0][t], b = keys_lds[1][t];
        part_keys[(m0 + t) * 4 + kz] = a < b ? a : b;
    }
}

// ---------------- epilogue: combine 4 k-splits, gather/scatter/loss --------
__global__ __launch_bounds__(256) void vq_epi(const u64* __restrict__ part_keys,
                                              const float* __restrict__ x,
                                              const float* __restrict__ dict,
                                              const float* __restrict__ rcnt,
                                              float* __restrict__ out_xq,
                                              float* __restrict__ new_dict,
                                              float* __restrict__ new_counts,
                                              float* __restrict__ loss_partials) {
    const int t = threadIdx.x;
    const int m0 = blockIdx.x * 64;
    __shared__ int ids_sh[64];
    __shared__ float lred[4];
    if (t < 64) {
        const u64* pk = part_keys + (size_t)(m0 + t) * 4;
        u64 best = pk[0];
        #pragma unroll
        for (int z = 1; z < 4; ++z) { const u64 k = pk[z]; if (k < best) best = k; }
        const int id = (int)(unsigned)(best & 0xffffffffu);
        ids_sh[t] = id;
        atomicAdd(&new_counts[id], 1.0f);
    }
    __syncthreads();
    float lsum = 0.0f;
    for (int r = 0; r < 64; ++r) {
        const int id = ids_sh[r];
        const float rc = rcnt[id];
        const float* drp = dict + (size_t)id * C_DIM;
        const float* xr = x + (size_t)(m0 + r) * C_DIM;
        float* oq = out_xq + (size_t)(m0 + r) * C_DIM;
        float* nd = new_dict + (size_t)id * C_DIM;
        #pragma unroll
        for (int h = 0; h < 2; ++h) {
            const int c = t + h * 256;
            const float e = drp[c] * rc;
            const float xv = xr[c];
            oq[c] = e;
            const float df = e - xv;
            lsum += df * df;
            atomicAdd(&nd[c], xv);
        }
    }
    #pragma unroll
    for (int off = 32; off > 0; off >>= 1) lsum += __shfl_down(lsum, off);
    if ((t & 63) == 0) lred[t >> 6] = lsum;
    __syncthreads();
    if (t == 0) loss_partials[blockIdx.x] = lred[0] + lred[1] + lred[2] + lred[3];
}

// ---------------- fallback fp32 path (verified in R1) ----------------------
__global__ __launch_bounds__(256) void vq_prep(const float* __restrict__ dict,
                                               const float* __restrict__ counts,
                                               float* __restrict__ en2,
                                               float* __restrict__ rcnt,
                                               float* __restrict__ new_dict,
                                               float* __restrict__ new_counts) {
    const int k = blockIdx.x;
    const int t = threadIdx.x;
    __shared__ float rc_sh;
    if (t == 0) {
        float c = counts[k];
        float rc = 1.0f / c;
        rc_sh = rc; rcnt[k] = rc; new_counts[k] = c * MOM;
    }
    __syncthreads();
    const float rc = rc_sh;
    const float* drow = dict + (size_t)k * C_DIM;
    float* ndrow = new_dict + (size_t)k * C_DIM;
    float d0 = drow[t], d1 = drow[t + 256];
    ndrow[t] = d0 * MOM; ndrow[t + 256] = d1 * MOM;
    float e0 = d0 * rc, e1 = d1 * rc;
    float s = e0 * e0 + e1 * e1;
    #pragma unroll
    for (int off = 32; off > 0; off >>= 1) s += __shfl_down(s, off);
    __shared__ float wsum[4];
    if ((t & 63) == 0) wsum[t >> 6] = s;
    __syncthreads();
    if (t == 0) en2[k] = wsum[0] + wsum[1] + wsum[2] + wsum[3];
}

__global__ __launch_bounds__(256) void vq_main(const float* __restrict__ x,
                                               const float* __restrict__ dict,
                                               const float* __restrict__ en2,
                                               const float* __restrict__ rcnt,
                                               float* __restrict__ out_xq,
                                               float* __restrict__ new_dict,
                                               float* __restrict__ new_counts,
                                               float* __restrict__ loss_partials) {
    __shared__ __align__(16) float xs[32][68];
    __shared__ __align__(16) float es[32][68];
    __shared__ float red_v[64][17];
    __shared__ int   red_i[64][17];
    __shared__ int   ids_sh[64];
    __shared__ float lred[4];

    const int t  = threadIdx.x;
    const int tx = t & 15;
    const int ty = t >> 4;
    const int m0 = blockIdx.x * 64;
    const int lr = t >> 2;
    const int lc = (t & 3) * 8;

    float bestv[4]; int besti[4];
    #pragma unroll
    for (int i = 0; i < 4; ++i) { bestv[i] = 1e30f; besti[i] = 0; }
    const float* xrow = x + (size_t)(m0 + lr) * C_DIM;

    for (int kt = 0; kt < K_VOCAB; kt += 64) {
        float acc[4][4] = {{0.f,0.f,0.f,0.f},{0.f,0.f,0.f,0.f},
                           {0.f,0.f,0.f,0.f},{0.f,0.f,0.f,0.f}};
        const float rcA = rcnt[kt + lr];
        const float* drow = dict + (size_t)(kt + lr) * C_DIM;
        for (int ct = 0; ct < C_DIM; ct += 32) {
            __syncthreads();
            #pragma unroll
            for (int h = 0; h < 2; ++h) {
                const float4 xv = *reinterpret_cast<const float4*>(xrow + ct + lc + h * 4);
                const float4 ev = *reinterpret_cast<const float4*>(drow + ct + lc + h * 4);
                const int cb = lc + h * 4;
                xs[cb + 0][lr] = xv.x; xs[cb + 1][lr] = xv.y;
                xs[cb + 2][lr] = xv.z; xs[cb + 3][lr] = xv.w;
                es[cb + 0][lr] = ev.x * rcA; es[cb + 1][lr] = ev.y * rcA;
                es[cb + 2][lr] = ev.z * rcA; es[cb + 3][lr] = ev.w * rcA;
            }
            __syncthreads();
            #pragma unroll
            for (int c = 0; c < 32; ++c) {
                const float4 xa = *reinterpret_cast<const float4*>(&xs[c][ty * 4]);
                const float4 eb = *reinterpret_cast<const float4*>(&es[c][tx * 4]);
                const float xr_[4] = {xa.x, xa.y, xa.z, xa.w};
                const float ec_[4] = {eb.x, eb.y, eb.z, eb.w};
                #pragma unroll
                for (int i = 0; i < 4; ++i)
                    #pragma unroll
                    for (int j = 0; j < 4; ++j)
                        acc[i][j] += xr_[i] * ec_[j];
            }
        }
        const float4 e4 = *reinterpret_cast<const float4*>(&en2[kt + tx * 4]);
        const float en_[4] = {e4.x, e4.y, e4.z, e4.w};
        #pragma unroll
        for (int i = 0; i < 4; ++i)
            #pragma unroll
            for (int j = 0; j < 4; ++j) {
                const float s = en_[j] - 2.0f * acc[i][j];
                if (s < bestv[i]) { bestv[i] = s; besti[i] = kt + tx * 4 + j; }
            }
    }
    #pragma unroll
    for (int i = 0; i < 4; ++i) {
        red_v[ty * 4 + i][tx] = bestv[i];
        red_i[ty * 4 + i][tx] = besti[i];
    }
    __syncthreads();
    if (t < 64) {
        float bv = red_v[t][0]; int bi = red_i[t][0];
        #pragma unroll
        for (int c = 1; c < 16; ++c) {
            const float v = red_v[t][c]; const int idx = red_i[t][c];
            if (v < bv || (v == bv && idx < bi)) { bv = v; bi = idx; }
        }
        ids_sh[t] = bi;
        atomicAdd(&new_counts[bi], 1.0f);
    }
    __syncthreads();
    float lsum = 0.0f;
    for (int r = 0; r < 64; ++r) {
        const int id = ids_sh[r];
        const float rc = rcnt[id];
        const float* dr = dict + (size_t)id * C_DIM;
        const float* xr = x + (size_t)(m0 + r) * C_DIM;
        float* oq = out_xq + (size_t)(m0 + r) * C_DIM;
        float* nd = new_dict + (size_t)id * C_DIM;
        #pragma unroll
        for (int h = 0; h < 2; ++h) {
            const int c = t + h * 256;
            const float e  = dr[c] * rc;
            const float xv = xr[c];
            oq[c] = e;
            const float df = e - xv;
            lsum += df * df;
            atomicAdd(&nd[c], xv);
        }
    }
    #pragma unroll
    for (int off = 32; off > 0; off >>= 1) lsum += __shfl_down(lsum, off);
    if ((t & 63) == 0) lred[t >> 6] = lsum;
    __syncthreads();
    if (t == 0) loss_partials[blockIdx.x] = lred[0] + lred[1] + lred[2] + lred[3];
}

// ---------------- finalize -------------------------------------------------
__global__ __launch_bounds__(256) void vq_finalize(const float* __restrict__ loss_partials,
                                                   const float* __restrict__ new_counts,
                                                   float* __restrict__ out_loss,
                                                   float* __restrict__ out_perp) {
    const int t = threadIdx.x;
    __shared__ double red[256];
    __shared__ double total_sh;

    double ls = 0.0;
    for (int i = t; i < 512; i += 256) ls += (double)loss_partials[i];
    red[t] = ls; __syncthreads();
    for (int off = 128; off > 0; off >>= 1) {
        if (t < off) red[t] += red[t + off];
        __syncthreads();
    }
    if (t == 0) *out_loss = (float)((double)BETA * red[0] / ((double)M_TOTAL * (double)C_DIM));
    __syncthreads();

    double cs = 0.0;
    for (int i = t; i < K_VOCAB; i += 256) cs += (double)new_counts[i];
    red[t] = cs; __syncthreads();
    for (int off = 128; off > 0; off >>= 1) {
        if (t < off) red[t] += red[t + off];
        __syncthreads();
    }
    if (t == 0) total_sh = red[0];
    __syncthreads();
    const float total = (float)total_sh;

    double es = 0.0;
    for (int i = t; i < K_VOCAB; i += 256) {
        const float p = new_counts[i] / total;
        es += (double)(p * logf(p + 1e-10f));
    }
    red[t] = es; __syncthreads();
    for (int off = 128; off > 0; off >>= 1) {
        if (t < off) red[t] += red[t + off];
        __syncthreads();
    }
    if (t == 0) *out_perp = (float)exp(-red[0]);
}

extern "C" void kernel_launch(void* const* d_in, const int* in_sizes, int n_in,
                              void* d_out, int out_size, void* d_ws, size_t ws_size,
                              hipStream_t stream) {
    const float* x      = (const float*)d_in[0];
    const float* dict   = (const float*)d_in[1];
    const float* counts = (const float*)d_in[2];

    float* out        = (float*)d_out;
    float* out_xq     = out;
    float* out_loss   = out + (size_t)M_TOTAL * C_DIM;
    float* out_perp   = out_loss + 1;
    float* new_dict   = out_perp + 1;
    float* new_counts = new_dict + (size_t)K_VOCAB * C_DIM;

    float* ws       = (float*)d_ws;
    float* en2      = ws;                         // 8192
    float* rcnt     = ws + K_VOCAB;               // 8192
    float* partials = ws + 2 * K_VOCAB;           // 512

    u64* part_keys = (u64*)(ws + 16896);          // byte 67584; 128K u64 = 1MB
    const size_t X2_off_f = 16896 + 262144;       // floats (16B aligned)
    const size_t X2_elems = (size_t)M_TOTAL * CK;
    const size_t E2_elems = (size_t)K_VOCAB * CK;
    const size_t need = X2_off_f * 4 + (X2_elems + E2_elems) * 2;

    if (ws_size >= need) {
        u16* X2 = (u16*)(ws + X2_off_f);
        u16* E2 = X2 + X2_elems;
        vq_prep_e<<<K_VOCAB, 256, 0, stream>>>(dict, counts, en2, rcnt, new_dict, new_counts, E2);
        vq_prep_x<<<2048, 256, 0, stream>>>(x, X2);
        vq_gemm8<<<1024, 256, 0, stream>>>(X2, E2, en2, part_keys);
        vq_epi<<<512, 256, 0, stream>>>(part_keys, x, dict, rcnt, out_xq,
                                        new_dict, new_counts, partials);
    } else {
        vq_prep<<<K_VOCAB, 256, 0, stream>>>(dict, counts, en2, rcnt, new_dict, new_counts);
        vq_main<<<M_TOTAL / 64, 256, 0, stream>>>(x, dict, en2, rcnt, out_xq,
                                                  new_dict, new_counts, partials);
    }
    vq_finalize<<<1, 256, 0, stream>>>(partials, new_counts, out_loss, out_perp);
}

// Round 13
// 656.840 us; speedup vs baseline: 1.1217x; 1.1217x over previous
//
#include <hip/hip_runtime.h>
#include <math.h>

#define M_TOTAL 32768   // 8 * 4096
#define C_DIM   512
#define K_VOCAB 8192
#define CK      1024    // 2*C_DIM: [hi | mid] bf16 split (3rd term ~2^-36, dropped)
#define MOM     0.995f
#define BETA    0.25f
#define NT      16      // code-tiles (256 codes) per k-half

typedef unsigned short u16;
typedef unsigned long long u64;
typedef short bf16x8 __attribute__((ext_vector_type(8)));
typedef float f32x4  __attribute__((ext_vector_type(4)));

// ---- helpers -------------------------------------------------------------
__device__ __forceinline__ u16 f2bf_rn(float f) {          // RN-even fp32->bf16
    unsigned u = __float_as_uint(f);
    u += 0x7fffu + ((u >> 16) & 1u);
    return (u16)(u >> 16);
}
__device__ __forceinline__ float bf2f(u16 h) { return __uint_as_float(((unsigned)h) << 16); }
__device__ __forceinline__ void split2(float v, u16& h0, u16& h1) {
    h0 = f2bf_rn(v);
    h1 = f2bf_rn(v - bf2f(h0));
}
__device__ __forceinline__ unsigned fkey(float f) {        // monotone float->uint
    unsigned u = __float_as_uint(f);
    return (u & 0x80000000u) ? ~u : (u | 0x80000000u);
}

// ---------------- fused prep: E-split + EMA inits + X-split ----------------
// blocks [0, K_VOCAB): per-code e=dict/counts, en2, E2 split, EMA init.
// blocks [K_VOCAB, K_VOCAB+2048): grid-stride 2-term split of x -> X2.
__global__ __launch_bounds__(256) void vq_prep_all(const float* __restrict__ dict,
                                                   const float* __restrict__ counts,
                                                   float* __restrict__ en2,
                                                   float* __restrict__ rcnt,
                                                   float* __restrict__ new_dict,
                                                   float* __restrict__ new_counts,
                                                   u16* __restrict__ E2,
                                                   const float* __restrict__ x,
                                                   u16* __restrict__ X2) {
    __shared__ float rc_sh;
    __shared__ float wsum[4];
    const int t = threadIdx.x;
    if (blockIdx.x < K_VOCAB) {
        const int k = blockIdx.x;
        if (t == 0) {
            float c = counts[k];
            float rc = 1.0f / c;
            rc_sh = rc; rcnt[k] = rc; new_counts[k] = c * MOM;
        }
        __syncthreads();
        const float rc = rc_sh;
        const float* dr = dict + (size_t)k * C_DIM;
        float* ndr = new_dict + (size_t)k * C_DIM;
        u16* er = E2 + (size_t)k * CK;
        float s = 0.f;
        #pragma unroll
        for (int h = 0; h < 2; ++h) {
            const int c = t + h * 256;
            const float d = dr[c];
            ndr[c] = d * MOM;
            const float e = d * rc;
            s += e * e;
            u16 h0, h1; split2(e, h0, h1);
            er[c] = h0; er[512 + c] = h1;
        }
        #pragma unroll
        for (int off = 32; off > 0; off >>= 1) s += __shfl_down(s, off);
        if ((t & 63) == 0) wsum[t >> 6] = s;
        __syncthreads();
        if (t == 0) en2[k] = wsum[0] + wsum[1] + wsum[2] + wsum[3];
    } else {
        const int xb = blockIdx.x - K_VOCAB;     // 0..2047
        const int total = M_TOTAL * C_DIM / 4;
        for (int i = xb * 256 + t; i < total; i += 2048 * 256) {
            const float4 v = ((const float4*)x)[i];
            const int m = i >> 7;
            const int c4 = (i & 127) << 2;
            u16* base = X2 + (size_t)m * CK + c4;
            ushort4 a, b;
            split2(v.x, a.x, b.x); split2(v.y, a.y, b.y);
            split2(v.z, a.z, b.z); split2(v.w, a.w, b.w);
            *(ushort4*)(base)       = a;
            *(ushort4*)(base + 512) = b;
        }
    }
}

// ---------------- main: pipelined MFMA GEMM + fused argmin (R8, verified) --
// 256 rows x 256 codes tile, BK=64, 8 waves (4M x 2N), wave tile 64x128.
// During tile T (reading buf T&1) stage tile T+1's ENTIRE A+B into buf
// (T+1)&1 (nobody reads it during T -- race-free). One waitcnt+barrier
// per K-tile. Conflict-free XOR swizzle (slot ^= row&7, verified 0 confl).
#define STAGE(par, gA, gB)                                                     \
    { _Pragma("unroll")                                                        \
      for (int q_ = 0; q_ < 4; ++q_) {                                         \
        __builtin_amdgcn_global_load_lds(                                      \
            (const __attribute__((address_space(1))) void*)(aB[q_] + (gA)),    \
            (__attribute__((address_space(3))) void*)                          \
                &lds[(par) * 32768 + (q_ * 512 + t) * 8], 16, 0, 0);           \
      }                                                                        \
      _Pragma("unroll")                                                        \
      for (int q_ = 0; q_ < 4; ++q_) {                                         \
        __builtin_amdgcn_global_load_lds(                                      \
            (const __attribute__((address_space(1))) void*)(bB[q_] + (gB)),    \
            (__attribute__((address_space(3))) void*)                          \
                &lds[(par) * 32768 + 16384 + (q_ * 512 + t) * 8], 16, 0, 0);   \
      } }

#define TILE(par)                                                              \
    {                                                                          \
        const size_t gA = (size_t)kc1 * 64;                                    \
        const size_t gB = (size_t)ct1 * (size_t)(256 * CK) + (size_t)kc1 * 64; \
        STAGE((par) ^ 1, gA, gB)                                               \
        bf16x8 af[4][2];                                                       \
        _Pragma("unroll") for (int mf = 0; mf < 4; ++mf)                       \
            _Pragma("unroll") for (int kk = 0; kk < 2; ++kk) {                 \
                const int row_ = arow[mf];                                     \
                af[mf][kk] = *(const bf16x8*)&lds[(par) * 32768 + row_ * 64 +  \
                               (((kk * 4 + l4) ^ (row_ & 7)) * 8)];            \
            }                                                                  \
        _Pragma("unroll") for (int nh = 0; nh < 2; ++nh) {                     \
            bf16x8 bfr[4][2];                                                  \
            _Pragma("unroll") for (int g = 0; g < 4; ++g)                      \
                _Pragma("unroll") for (int kk = 0; kk < 2; ++kk) {             \
                    const int row_ = brow[nh * 4 + g];                         \
                    bfr[g][kk] = *(const bf16x8*)&lds[(par) * 32768 + 16384 +  \
                                   row_ * 64 + (((kk * 4 + l4) ^ (row_ & 7)) * 8)]; \
                }                                                              \
            __builtin_amdgcn_s_setprio(1);                                     \
            _Pragma("unroll") for (int kk = 0; kk < 2; ++kk)                   \
                _Pragma("unroll") for (int mf = 0; mf < 4; ++mf)               \
                    _Pragma("unroll") for (int g = 0; g < 4; ++g)              \
                        acc[mf][nh * 4 + g] =                                  \
                            __builtin_amdgcn_mfma_f32_16x16x32_bf16(           \
                                af[mf][kk], bfr[g][kk],                        \
                                acc[mf][nh * 4 + g], 0, 0, 0);                 \
            __builtin_amdgcn_s_setprio(0);                                     \
        }                                                                      \
        asm volatile("s_waitcnt vmcnt(0) lgkmcnt(0)" ::: "memory");            \
        if (++kc1 == 16) { kc1 = 0; ct1 = (ct1 + 1) & 15; }                    \
        asm volatile("s_barrier" ::: "memory");                                \
    }

__global__ __launch_bounds__(512, 1) void vq_gemm8(const u16* __restrict__ X2,
                                                   const u16* __restrict__ E2,
                                                   const float* __restrict__ en2,
                                                   u64* __restrict__ part_keys) {
    __shared__ __align__(16) u16 lds[65536];      // 128 KB: 2 bufs x (A 32KB | B 32KB)
    __shared__ float en2_s[4096];
    __shared__ u64 keys_lds[2][256];

    const int t = threadIdx.x;
    const int lane = t & 63;
    const int wid = t >> 6;
    const int wm = wid >> 1, wn = wid & 1;        // 4M x 2N wave grid
    const int l15 = lane & 15, l4 = lane >> 4;

    const int wg = ((blockIdx.x & 7) << 5) | (blockIdx.x >> 3);  // XCD swizzle
    const int mt = wg & 127;
    const int kz = wg >> 7;
    const size_t m0 = (size_t)mt * 256;
    const int kbase = kz * 4096;

    for (int i = t; i < 4096; i += 512) en2_s[i] = en2[kbase + i];

    // staging: chunk ci = q*512+t -> row ci>>3, slot ci&7 (8 x 16B per 128B row);
    // linear LDS dest, inverse-swizzled global source (both-sides swizzle)
    const u16* aB[4]; const u16* bB[4];
    #pragma unroll
    for (int q = 0; q < 4; ++q) {
        const int ci = q * 512 + t;
        const int row = ci >> 3;
        const int sx = ((ci & 7) ^ (row & 7)) * 8;
        aB[q] = X2 + (m0 + row) * CK + sx;
        bB[q] = E2 + ((size_t)(kbase + row)) * CK + sx;
    }
    // fragment rows
    int arow[4], brow[8];
    #pragma unroll
    for (int mf = 0; mf < 4; ++mf) arow[mf] = wm * 64 + mf * 16 + l15;
    #pragma unroll
    for (int jn = 0; jn < 8; ++jn) brow[jn] = wn * 128 + jn * 16 + l15;

    f32x4 acc[4][8];
    u64 keys[16];
    #pragma unroll
    for (int s = 0; s < 16; ++s) keys[s] = ~0ull;

    // prologue: stage tile 0 into buf0
    STAGE(0, 0, 0)
    asm volatile("s_waitcnt vmcnt(0) lgkmcnt(0)" ::: "memory");
    asm volatile("s_barrier" ::: "memory");

    int kc1 = 1, ct1 = 0;   // coords of next tile to stage

    for (int ct = 0; ct < NT; ++ct) {
        const f32x4 z4 = {0.f, 0.f, 0.f, 0.f};
        #pragma unroll
        for (int i = 0; i < 4; ++i)
            #pragma unroll
            for (int j = 0; j < 8; ++j) acc[i][j] = z4;

        #pragma unroll 1
        for (int kp = 0; kp < 8; ++kp) {        // 16 K-tiles per code-tile
            TILE(0)
            TILE(1)
        }
        // fused score + running argmin for this 256-code tile (en2 via LDS)
        #pragma unroll
        for (int jn = 0; jn < 8; ++jn) {
            const int cl = ct * 256 + wn * 128 + jn * 16 + l15;
            const float e2 = en2_s[cl];
            const unsigned cid = (unsigned)(kbase + cl);
            #pragma unroll
            for (int im = 0; im < 4; ++im)
                #pragma unroll
                for (int r = 0; r < 4; ++r) {
                    const float sc = fmaf(-2.0f, acc[im][jn][r], e2);
                    const u64 k = (((u64)fkey(sc)) << 32) | cid;
                    if (k < keys[im * 4 + r]) keys[im * 4 + r] = k;
                }
        }
    }

    // in-wave reduce across the 16 lanes (codes) of each row group
    #pragma unroll
    for (int s = 0; s < 16; ++s)
        #pragma unroll
        for (int mm = 1; mm < 16; mm <<= 1) {
            const u64 o = __shfl_xor(keys[s], mm);
            if (o < keys[s]) keys[s] = o;
        }
    if (l15 == 0) {
        #pragma unroll
        for (int im = 0; im < 4; ++im)
            #pragma unroll
            for (int r = 0; r < 4; ++r)
                keys_lds[wn][wm * 64 + im * 16 + l4 * 4 + r] = keys[im * 4 + r];
    }
    __syncthreads();
    if (t < 256) {
        const u64 a = keys_lds[0][t], b = keys_lds[1][t];
        part_keys[(m0 + t) * 2 + kz] = a < b ? a : b;
    }
}

// ---------------- epilogue: combine k-halves, gather/scatter/loss ----------
// 1024 blocks x 32 rows (was 512x64): halves per-block serial gather time.
__global__ __launch_bounds__(256) void vq_epi(const u64* __restrict__ part_keys,
                                              const float* __restrict__ x,
                                              const float* __restrict__ dict,
                                              const float* __restrict__ rcnt,
                                              float* __restrict__ out_xq,
                                              float* __restrict__ new_dict,
                                              float* __restrict__ new_counts,
                                              float* __restrict__ loss_partials) {
    const int t = threadIdx.x;
    const int m0 = blockIdx.x * 32;
    __shared__ int ids_sh[32];
    __shared__ float lred[4];
    if (t < 32) {
        const u64 a = part_keys[(size_t)(m0 + t) * 2];
        const u64 b = part_keys[(size_t)(m0 + t) * 2 + 1];
        const int id = (int)(unsigned)((a < b ? a : b) & 0xffffffffu);
        ids_sh[t] = id;
        atomicAdd(&new_counts[id], 1.0f);
    }
    __syncthreads();
    float lsum = 0.0f;
    for (int r = 0; r < 32; ++r) {
        const int id = ids_sh[r];
        const float rc = rcnt[id];
        const float* drp = dict + (size_t)id * C_DIM;
        const float* xr = x + (size_t)(m0 + r) * C_DIM;
        float* oq = out_xq + (size_t)(m0 + r) * C_DIM;
        float* nd = new_dict + (size_t)id * C_DIM;
        #pragma unroll
        for (int h = 0; h < 2; ++h) {
            const int c = t + h * 256;
            const float e = drp[c] * rc;
            const float xv = xr[c];
            oq[c] = e;
            const float df = e - xv;
            lsum += df * df;
            atomicAdd(&nd[c], xv);
        }
    }
    #pragma unroll
    for (int off = 32; off > 0; off >>= 1) lsum += __shfl_down(lsum, off);
    if ((t & 63) == 0) lred[t >> 6] = lsum;
    __syncthreads();
    if (t == 0) loss_partials[blockIdx.x] = lred[0] + lred[1] + lred[2] + lred[3];
}

// ---------------- fallback fp32 path (verified in R1) ----------------------
__global__ __launch_bounds__(256) void vq_prep(const float* __restrict__ dict,
                                               const float* __restrict__ counts,
                                               float* __restrict__ en2,
                                               float* __restrict__ rcnt,
                                               float* __restrict__ new_dict,
                                               float* __restrict__ new_counts) {
    const int k = blockIdx.x;
    const int t = threadIdx.x;
    __shared__ float rc_sh;
    if (t == 0) {
        float c = counts[k];
        float rc = 1.0f / c;
        rc_sh = rc; rcnt[k] = rc; new_counts[k] = c * MOM;
    }
    __syncthreads();
    const float rc = rc_sh;
    const float* drow = dict + (size_t)k * C_DIM;
    float* ndrow = new_dict + (size_t)k * C_DIM;
    float d0 = drow[t], d1 = drow[t + 256];
    ndrow[t] = d0 * MOM; ndrow[t + 256] = d1 * MOM;
    float e0 = d0 * rc, e1 = d1 * rc;
    float s = e0 * e0 + e1 * e1;
    #pragma unroll
    for (int off = 32; off > 0; off >>= 1) s += __shfl_down(s, off);
    __shared__ float wsum[4];
    if ((t & 63) == 0) wsum[t >> 6] = s;
    __syncthreads();
    if (t == 0) en2[k] = wsum[0] + wsum[1] + wsum[2] + wsum[3];
}

__global__ __launch_bounds__(256) void vq_main(const float* __restrict__ x,
                                               const float* __restrict__ dict,
                                               const float* __restrict__ en2,
                                               const float* __restrict__ rcnt,
                                               float* __restrict__ out_xq,
                                               float* __restrict__ new_dict,
                                               float* __restrict__ new_counts,
                                               float* __restrict__ loss_partials) {
    __shared__ __align__(16) float xs[32][68];
    __shared__ __align__(16) float es[32][68];
    __shared__ float red_v[64][17];
    __shared__ int   red_i[64][17];
    __shared__ int   ids_sh[64];
    __shared__ float lred[4];

    const int t  = threadIdx.x;
    const int tx = t & 15;
    const int ty = t >> 4;
    const int m0 = blockIdx.x * 64;
    const int lr = t >> 2;
    const int lc = (t & 3) * 8;

    float bestv[4]; int besti[4];
    #pragma unroll
    for (int i = 0; i < 4; ++i) { bestv[i] = 1e30f; besti[i] = 0; }
    const float* xrow = x + (size_t)(m0 + lr) * C_DIM;

    for (int kt = 0; kt < K_VOCAB; kt += 64) {
        float acc[4][4] = {{0.f,0.f,0.f,0.f},{0.f,0.f,0.f,0.f},
                           {0.f,0.f,0.f,0.f},{0.f,0.f,0.f,0.f}};
        const float rcA = rcnt[kt + lr];
        const float* drow = dict + (size_t)(kt + lr) * C_DIM;
        for (int ct = 0; ct < C_DIM; ct += 32) {
            __syncthreads();
            #pragma unroll
            for (int h = 0; h < 2; ++h) {
                const float4 xv = *reinterpret_cast<const float4*>(xrow + ct + lc + h * 4);
                const float4 ev = *reinterpret_cast<const float4*>(drow + ct + lc + h * 4);
                const int cb = lc + h * 4;
                xs[cb + 0][lr] = xv.x; xs[cb + 1][lr] = xv.y;
                xs[cb + 2][lr] = xv.z; xs[cb + 3][lr] = xv.w;
                es[cb + 0][lr] = ev.x * rcA; es[cb + 1][lr] = ev.y * rcA;
                es[cb + 2][lr] = ev.z * rcA; es[cb + 3][lr] = ev.w * rcA;
            }
            __syncthreads();
            #pragma unroll
            for (int c = 0; c < 32; ++c) {
                const float4 xa = *reinterpret_cast<const float4*>(&xs[c][ty * 4]);
                const float4 eb = *reinterpret_cast<const float4*>(&es[c][tx * 4]);
                const float xr_[4] = {xa.x, xa.y, xa.z, xa.w};
                const float ec_[4] = {eb.x, eb.y, eb.z, eb.w};
                #pragma unroll
                for (int i = 0; i < 4; ++i)
                    #pragma unroll
                    for (int j = 0; j < 4; ++j)
                        acc[i][j] += xr_[i] * ec_[j];
            }
        }
        const float4 e4 = *reinterpret_cast<const float4*>(&en2[kt + tx * 4]);
        const float en_[4] = {e4.x, e4.y, e4.z, e4.w};
        #pragma unroll
        for (int i = 0; i < 4; ++i)
            #pragma unroll
            for (int j = 0; j < 4; ++j) {
                const float s = en_[j] - 2.0f * acc[i][j];
                if (s < bestv[i]) { bestv[i] = s; besti[i] = kt + tx * 4 + j; }
            }
    }
    #pragma unroll
    for (int i = 0; i < 4; ++i) {
        red_v[ty * 4 + i][tx] = bestv[i];
        red_i[ty * 4 + i][tx] = besti[i];
    }
    __syncthreads();
    if (t < 64) {
        float bv = red_v[t][0]; int bi = red_i[t][0];
        #pragma unroll
        for (int c = 1; c < 16; ++c) {
            const float v = red_v[t][c]; const int idx = red_i[t][c];
            if (v < bv || (v == bv && idx < bi)) { bv = v; bi = idx; }
        }
        ids_sh[t] = bi;
        atomicAdd(&new_counts[bi], 1.0f);
    }
    __syncthreads();
    float lsum = 0.0f;
    for (int r = 0; r < 64; ++r) {
        const int id = ids_sh[r];
        const float rc = rcnt[id];
        const float* dr = dict + (size_t)id * C_DIM;
        const float* xr = x + (size_t)(m0 + r) * C_DIM;
        float* oq = out_xq + (size_t)(m0 + r) * C_DIM;
        float* nd = new_dict + (size_t)id * C_DIM;
        #pragma unroll
        for (int h = 0; h < 2; ++h) {
            const int c = t + h * 256;
            const float e  = dr[c] * rc;
            const float xv = xr[c];
            oq[c] = e;
            const float df = e - xv;
            lsum += df * df;
            atomicAdd(&nd[c], xv);
        }
    }
    #pragma unroll
    for (int off = 32; off > 0; off >>= 1) lsum += __shfl_down(lsum, off);
    if ((t & 63) == 0) lred[t >> 6] = lsum;
    __syncthreads();
    if (t == 0) loss_partials[blockIdx.x] = lred[0] + lred[1] + lred[2] + lred[3];
}

// ---------------- finalize: loss, perplexity -------------------------------
__global__ __launch_bounds__(256) void vq_finalize(const float* __restrict__ loss_partials,
                                                   const float* __restrict__ new_counts,
                                                   float* __restrict__ out_loss,
                                                   float* __restrict__ out_perp,
                                                   int n_partials) {
    const int t = threadIdx.x;
    __shared__ double red[256];
    __shared__ double total_sh;

    double ls = 0.0;
    for (int i = t; i < n_partials; i += 256) ls += (double)loss_partials[i];
    red[t] = ls; __syncthreads();
    for (int off = 128; off > 0; off >>= 1) {
        if (t < off) red[t] += red[t + off];
        __syncthreads();
    }
    if (t == 0) *out_loss = (float)((double)BETA * red[0] / ((double)M_TOTAL * (double)C_DIM));
    __syncthreads();

    double cs = 0.0;
    for (int i = t; i < K_VOCAB; i += 256) cs += (double)new_counts[i];
    red[t] = cs; __syncthreads();
    for (int off = 128; off > 0; off >>= 1) {
        if (t < off) red[t] += red[t + off];
        __syncthreads();
    }
    if (t == 0) total_sh = red[0];
    __syncthreads();
    const float total = (float)total_sh;

    double es = 0.0;
    for (int i = t; i < K_VOCAB; i += 256) {
        const float p = new_counts[i] / total;
        es += (double)(p * logf(p + 1e-10f));
    }
    red[t] = es; __syncthreads();
    for (int off = 128; off > 0; off >>= 1) {
        if (t < off) red[t] += red[t + off];
        __syncthreads();
    }
    if (t == 0) *out_perp = (float)exp(-red[0]);
}

extern "C" void kernel_launch(void* const* d_in, const int* in_sizes, int n_in,
                              void* d_out, int out_size, void* d_ws, size_t ws_size,
                              hipStream_t stream) {
    const float* x      = (const float*)d_in[0];
    const float* dict   = (const float*)d_in[1];
    const float* counts = (const float*)d_in[2];

    float* out        = (float*)d_out;
    float* out_xq     = out;
    float* out_loss   = out + (size_t)M_TOTAL * C_DIM;
    float* out_perp   = out_loss + 1;
    float* new_dict   = out_perp + 1;
    float* new_counts = new_dict + (size_t)K_VOCAB * C_DIM;

    float* ws       = (float*)d_ws;
    float* en2      = ws;                         // 8192
    float* rcnt     = ws + K_VOCAB;               // 8192
    float* partials = ws + 2 * K_VOCAB;           // 1024

    u64* part_keys = (u64*)(ws + 17408);          // byte 69632; 64K u64 = 512KB
    const size_t X2_off_f = 17408 + 131072;       // 148480 floats (16B aligned)
    const size_t X2_elems = (size_t)M_TOTAL * CK;
    const size_t E2_elems = (size_t)K_VOCAB * CK;
    const size_t need = X2_off_f * 4 + (X2_elems + E2_elems) * 2;

    if (ws_size >= need) {
        u16* X2 = (u16*)(ws + X2_off_f);
        u16* E2 = X2 + X2_elems;
        vq_prep_all<<<K_VOCAB + 2048, 256, 0, stream>>>(dict, counts, en2, rcnt,
                                                        new_dict, new_counts, E2, x, X2);
        vq_gemm8<<<256, 512, 0, stream>>>(X2, E2, en2, part_keys);
        vq_epi<<<1024, 256, 0, stream>>>(part_keys, x, dict, rcnt, out_xq,
                                         new_dict, new_counts, partials);
        vq_finalize<<<1, 256, 0, stream>>>(partials, new_counts, out_loss, out_perp, 1024);
    } else {
        vq_prep<<<K_VOCAB, 256, 0, stream>>>(dict, counts, en2, rcnt, new_dict, new_counts);
        vq_main<<<M_TOTAL / 64, 256, 0, stream>>>(x, dict, en2, rcnt, out_xq,
                                                  new_dict, new_counts, partials);
        vq_finalize<<<1, 256, 0, stream>>>(partials, new_counts, out_loss, out_perp, 512);
    }
}

// Round 14
// 451.163 us; speedup vs baseline: 1.6331x; 1.4559x over previous
//
#include <hip/hip_runtime.h>
#include <math.h>

#define M_TOTAL 32768   // 8 * 4096
#define C_DIM   512
#define K_VOCAB 8192
#define CK      512     // plain bf16 (1-term): cross-terms dominate error anyway
#define MOM     0.995f
#define BETA    0.25f
#define NT      16      // code-tiles (256 codes) per k-half

typedef unsigned short u16;
typedef unsigned long long u64;
typedef short bf16x8 __attribute__((ext_vector_type(8)));
typedef float f32x4  __attribute__((ext_vector_type(4)));

// ---- helpers -------------------------------------------------------------
__device__ __forceinline__ u16 f2bf_rn(float f) {          // RN-even fp32->bf16
    unsigned u = __float_as_uint(f);
    u += 0x7fffu + ((u >> 16) & 1u);
    return (u16)(u >> 16);
}
__device__ __forceinline__ unsigned fkey(float f) {        // monotone float->uint
    unsigned u = __float_as_uint(f);
    return (u & 0x80000000u) ? ~u : (u | 0x80000000u);
}

// ---------------- fused prep: E-split + EMA inits + X-split ----------------
// blocks [0, K_VOCAB): per-code e=dict/counts, en2, E2 bf16, EMA init.
// blocks [K_VOCAB, K_VOCAB+2048): grid-stride bf16 cast of x -> X2.
__global__ __launch_bounds__(256) void vq_prep_all(const float* __restrict__ dict,
                                                   const float* __restrict__ counts,
                                                   float* __restrict__ en2,
                                                   float* __restrict__ rcnt,
                                                   float* __restrict__ new_dict,
                                                   float* __restrict__ new_counts,
                                                   u16* __restrict__ E2,
                                                   const float* __restrict__ x,
                                                   u16* __restrict__ X2) {
    __shared__ float rc_sh;
    __shared__ float wsum[4];
    const int t = threadIdx.x;
    if (blockIdx.x < K_VOCAB) {
        const int k = blockIdx.x;
        if (t == 0) {
            float c = counts[k];
            float rc = 1.0f / c;
            rc_sh = rc; rcnt[k] = rc; new_counts[k] = c * MOM;
        }
        __syncthreads();
        const float rc = rc_sh;
        const float* dr = dict + (size_t)k * C_DIM;
        float* ndr = new_dict + (size_t)k * C_DIM;
        u16* er = E2 + (size_t)k * CK;
        float s = 0.f;
        #pragma unroll
        for (int h = 0; h < 2; ++h) {
            const int c = t + h * 256;
            const float d = dr[c];
            ndr[c] = d * MOM;
            const float e = d * rc;
            s += e * e;
            er[c] = f2bf_rn(e);
        }
        #pragma unroll
        for (int off = 32; off > 0; off >>= 1) s += __shfl_down(s, off);
        if ((t & 63) == 0) wsum[t >> 6] = s;
        __syncthreads();
        if (t == 0) en2[k] = wsum[0] + wsum[1] + wsum[2] + wsum[3];
    } else {
        const int xb = blockIdx.x - K_VOCAB;     // 0..2047
        const int total = M_TOTAL * C_DIM / 4;
        for (int i = xb * 256 + t; i < total; i += 2048 * 256) {
            const float4 v = ((const float4*)x)[i];
            const int m = i >> 7;
            const int c4 = (i & 127) << 2;
            ushort4 a;
            a.x = f2bf_rn(v.x); a.y = f2bf_rn(v.y);
            a.z = f2bf_rn(v.z); a.w = f2bf_rn(v.w);
            *(ushort4*)(X2 + (size_t)m * CK + c4) = a;
        }
    }
}

// ---------------- main: pipelined MFMA GEMM + fused argmin (R8, verified) --
// 256 rows x 256 codes tile, BK=64, 8 waves (4M x 2N), wave tile 64x128.
// During tile T (reading buf T&1) stage tile T+1's ENTIRE A+B into buf
// (T+1)&1 (nobody reads it during T -- race-free). One waitcnt+barrier
// per K-tile. Conflict-free XOR swizzle (slot ^= row&7, verified 0 confl).
#define STAGE(par, gA, gB)                                                     \
    { _Pragma("unroll")                                                        \
      for (int q_ = 0; q_ < 4; ++q_) {                                         \
        __builtin_amdgcn_global_load_lds(                                      \
            (const __attribute__((address_space(1))) void*)(aB[q_] + (gA)),    \
            (__attribute__((address_space(3))) void*)                          \
                &lds[(par) * 32768 + (q_ * 512 + t) * 8], 16, 0, 0);           \
      }                                                                        \
      _Pragma("unroll")                                                        \
      for (int q_ = 0; q_ < 4; ++q_) {                                         \
        __builtin_amdgcn_global_load_lds(                                      \
            (const __attribute__((address_space(1))) void*)(bB[q_] + (gB)),    \
            (__attribute__((address_space(3))) void*)                          \
                &lds[(par) * 32768 + 16384 + (q_ * 512 + t) * 8], 16, 0, 0);   \
      } }

#define TILE(par)                                                              \
    {                                                                          \
        const size_t gA = (size_t)kc1 * 64;                                    \
        const size_t gB = (size_t)ct1 * (size_t)(256 * CK) + (size_t)kc1 * 64; \
        STAGE((par) ^ 1, gA, gB)                                               \
        bf16x8 af[4][2];                                                       \
        _Pragma("unroll") for (int mf = 0; mf < 4; ++mf)                       \
            _Pragma("unroll") for (int kk = 0; kk < 2; ++kk) {                 \
                const int row_ = arow[mf];                                     \
                af[mf][kk] = *(const bf16x8*)&lds[(par) * 32768 + row_ * 64 +  \
                               (((kk * 4 + l4) ^ (row_ & 7)) * 8)];            \
            }                                                                  \
        _Pragma("unroll") for (int nh = 0; nh < 2; ++nh) {                     \
            bf16x8 bfr[4][2];                                                  \
            _Pragma("unroll") for (int g = 0; g < 4; ++g)                      \
                _Pragma("unroll") for (int kk = 0; kk < 2; ++kk) {             \
                    const int row_ = brow[nh * 4 + g];                         \
                    bfr[g][kk] = *(const bf16x8*)&lds[(par) * 32768 + 16384 +  \
                                   row_ * 64 + (((kk * 4 + l4) ^ (row_ & 7)) * 8)]; \
                }                                                              \
            __builtin_amdgcn_s_setprio(1);                                     \
            _Pragma("unroll") for (int kk = 0; kk < 2; ++kk)                   \
                _Pragma("unroll") for (int mf = 0; mf < 4; ++mf)               \
                    _Pragma("unroll") for (int g = 0; g < 4; ++g)              \
                        acc[mf][nh * 4 + g] =                                  \
                            __builtin_amdgcn_mfma_f32_16x16x32_bf16(           \
                                af[mf][kk], bfr[g][kk],                        \
                                acc[mf][nh * 4 + g], 0, 0, 0);                 \
            __builtin_amdgcn_s_setprio(0);                                     \
        }                                                                      \
        asm volatile("s_waitcnt vmcnt(0) lgkmcnt(0)" ::: "memory");            \
        if (++kc1 == 8) { kc1 = 0; ct1 = (ct1 + 1) & 15; }                     \
        asm volatile("s_barrier" ::: "memory");                                \
    }

__global__ __launch_bounds__(512, 1) void vq_gemm8(const u16* __restrict__ X2,
                                                   const u16* __restrict__ E2,
                                                   const float* __restrict__ en2,
                                                   u64* __restrict__ part_keys) {
    __shared__ __align__(16) u16 lds[65536];      // 128 KB: 2 bufs x (A 32KB | B 32KB)
    __shared__ float en2_s[4096];
    __shared__ u64 keys_lds[2][256];

    const int t = threadIdx.x;
    const int lane = t & 63;
    const int wid = t >> 6;
    const int wm = wid >> 1, wn = wid & 1;        // 4M x 2N wave grid
    const int l15 = lane & 15, l4 = lane >> 4;

    const int wg = ((blockIdx.x & 7) << 5) | (blockIdx.x >> 3);  // XCD swizzle
    const int mt = wg & 127;
    const int kz = wg >> 7;
    const size_t m0 = (size_t)mt * 256;
    const int kbase = kz * 4096;

    for (int i = t; i < 4096; i += 512) en2_s[i] = en2[kbase + i];

    // staging: chunk ci = q*512+t -> row ci>>3, slot ci&7 (8 x 16B per 128B row);
    // linear LDS dest, inverse-swizzled global source (both-sides swizzle)
    const u16* aB[4]; const u16* bB[4];
    #pragma unroll
    for (int q = 0; q < 4; ++q) {
        const int ci = q * 512 + t;
        const int row = ci >> 3;
        const int sx = ((ci & 7) ^ (row & 7)) * 8;
        aB[q] = X2 + (m0 + row) * CK + sx;
        bB[q] = E2 + ((size_t)(kbase + row)) * CK + sx;
    }
    // fragment rows
    int arow[4], brow[8];
    #pragma unroll
    for (int mf = 0; mf < 4; ++mf) arow[mf] = wm * 64 + mf * 16 + l15;
    #pragma unroll
    for (int jn = 0; jn < 8; ++jn) brow[jn] = wn * 128 + jn * 16 + l15;

    f32x4 acc[4][8];
    u64 keys[16];
    #pragma unroll
    for (int s = 0; s < 16; ++s) keys[s] = ~0ull;

    // prologue: stage tile 0 into buf0
    STAGE(0, 0, 0)
    asm volatile("s_waitcnt vmcnt(0) lgkmcnt(0)" ::: "memory");
    asm volatile("s_barrier" ::: "memory");

    int kc1 = 1, ct1 = 0;   // coords of next tile to stage

    for (int ct = 0; ct < NT; ++ct) {
        const f32x4 z4 = {0.f, 0.f, 0.f, 0.f};
        #pragma unroll
        for (int i = 0; i < 4; ++i)
            #pragma unroll
            for (int j = 0; j < 8; ++j) acc[i][j] = z4;

        #pragma unroll 1
        for (int kp = 0; kp < 4; ++kp) {        // 8 K-tiles per code-tile
            TILE(0)
            TILE(1)
        }
        // fused score + running argmin for this 256-code tile (en2 via LDS)
        #pragma unroll
        for (int jn = 0; jn < 8; ++jn) {
            const int cl = ct * 256 + wn * 128 + jn * 16 + l15;
            const float e2 = en2_s[cl];
            const unsigned cid = (unsigned)(kbase + cl);
            #pragma unroll
            for (int im = 0; im < 4; ++im)
                #pragma unroll
                for (int r = 0; r < 4; ++r) {
                    const float sc = fmaf(-2.0f, acc[im][jn][r], e2);
                    const u64 k = (((u64)fkey(sc)) << 32) | cid;
                    if (k < keys[im * 4 + r]) keys[im * 4 + r] = k;
                }
        }
    }

    // in-wave reduce across the 16 lanes (codes) of each row group
    #pragma unroll
    for (int s = 0; s < 16; ++s)
        #pragma unroll
        for (int mm = 1; mm < 16; mm <<= 1) {
            const u64 o = __shfl_xor(keys[s], mm);
            if (o < keys[s]) keys[s] = o;
        }
    if (l15 == 0) {
        #pragma unroll
        for (int im = 0; im < 4; ++im)
            #pragma unroll
            for (int r = 0; r < 4; ++r)
                keys_lds[wn][wm * 64 + im * 16 + l4 * 4 + r] = keys[im * 4 + r];
    }
    __syncthreads();
    if (t < 256) {
        const u64 a = keys_lds[0][t], b = keys_lds[1][t];
        part_keys[(m0 + t) * 2 + kz] = a < b ? a : b;
    }
}

// ---------------- epilogue: combine k-halves, gather/scatter/loss ----------
__global__ __launch_bounds__(256) void vq_epi(const u64* __restrict__ part_keys,
                                              const float* __restrict__ x,
                                              const float* __restrict__ dict,
                                              const float* __restrict__ rcnt,
                                              float* __restrict__ out_xq,
                                              float* __restrict__ new_dict,
                                              float* __restrict__ new_counts,
                                              float* __restrict__ loss_partials) {
    const int t = threadIdx.x;
    const int m0 = blockIdx.x * 32;
    __shared__ int ids_sh[32];
    __shared__ float lred[4];
    if (t < 32) {
        const u64 a = part_keys[(size_t)(m0 + t) * 2];
        const u64 b = part_keys[(size_t)(m0 + t) * 2 + 1];
        const int id = (int)(unsigned)((a < b ? a : b) & 0xffffffffu);
        ids_sh[t] = id;
        atomicAdd(&new_counts[id], 1.0f);
    }
    __syncthreads();
    float lsum = 0.0f;
    for (int r = 0; r < 32; ++r) {
        const int id = ids_sh[r];
        const float rc = rcnt[id];
        const float* drp = dict + (size_t)id * C_DIM;
        const float* xr = x + (size_t)(m0 + r) * C_DIM;
        float* oq = out_xq + (size_t)(m0 + r) * C_DIM;
        float* nd = new_dict + (size_t)id * C_DIM;
        #pragma unroll
        for (int h = 0; h < 2; ++h) {
            const int c = t + h * 256;
            const float e = drp[c] * rc;
            const float xv = xr[c];
            oq[c] = e;
            const float df = e - xv;
            lsum += df * df;
            atomicAdd(&nd[c], xv);
        }
    }
    #pragma unroll
    for (int off = 32; off > 0; off >>= 1) lsum += __shfl_down(lsum, off);
    if ((t & 63) == 0) lred[t >> 6] = lsum;
    __syncthreads();
    if (t == 0) loss_partials[blockIdx.x] = lred[0] + lred[1] + lred[2] + lred[3];
}

// ---------------- fallback fp32 path (verified in R1) ----------------------
__global__ __launch_bounds__(256) void vq_prep(const float* __restrict__ dict,
                                               const float* __restrict__ counts,
                                               float* __restrict__ en2,
                                               float* __restrict__ rcnt,
                                               float* __restrict__ new_dict,
                                               float* __restrict__ new_counts) {
    const int k = blockIdx.x;
    const int t = threadIdx.x;
    __shared__ float rc_sh;
    if (t == 0) {
        float c = counts[k];
        float rc = 1.0f / c;
        rc_sh = rc; rcnt[k] = rc; new_counts[k] = c * MOM;
    }
    __syncthreads();
    const float rc = rc_sh;
    const float* drow = dict + (size_t)k * C_DIM;
    float* ndrow = new_dict + (size_t)k * C_DIM;
    float d0 = drow[t], d1 = drow[t + 256];
    ndrow[t] = d0 * MOM; ndrow[t + 256] = d1 * MOM;
    float e0 = d0 * rc, e1 = d1 * rc;
    float s = e0 * e0 + e1 * e1;
    #pragma unroll
    for (int off = 32; off > 0; off >>= 1) s += __shfl_down(s, off);
    __shared__ float wsum[4];
    if ((t & 63) == 0) wsum[t >> 6] = s;
    __syncthreads();
    if (t == 0) en2[k] = wsum[0] + wsum[1] + wsum[2] + wsum[3];
}

__global__ __launch_bounds__(256) void vq_main(const float* __restrict__ x,
                                               const float* __restrict__ dict,
                                               const float* __restrict__ en2,
                                               const float* __restrict__ rcnt,
                                               float* __restrict__ out_xq,
                                               float* __restrict__ new_dict,
                                               float* __restrict__ new_counts,
                                               float* __restrict__ loss_partials) {
    __shared__ __align__(16) float xs[32][68];
    __shared__ __align__(16) float es[32][68];
    __shared__ float red_v[64][17];
    __shared__ int   red_i[64][17];
    __shared__ int   ids_sh[64];
    __shared__ float lred[4];

    const int t  = threadIdx.x;
    const int tx = t & 15;
    const int ty = t >> 4;
    const int m0 = blockIdx.x * 64;
    const int lr = t >> 2;
    const int lc = (t & 3) * 8;

    float bestv[4]; int besti[4];
    #pragma unroll
    for (int i = 0; i < 4; ++i) { bestv[i] = 1e30f; besti[i] = 0; }
    const float* xrow = x + (size_t)(m0 + lr) * C_DIM;

    for (int kt = 0; kt < K_VOCAB; kt += 64) {
        float acc[4][4] = {{0.f,0.f,0.f,0.f},{0.f,0.f,0.f,0.f},
                           {0.f,0.f,0.f,0.f},{0.f,0.f,0.f,0.f}};
        const float rcA = rcnt[kt + lr];
        const float* drow = dict + (size_t)(kt + lr) * C_DIM;
        for (int ct = 0; ct < C_DIM; ct += 32) {
            __syncthreads();
            #pragma unroll
            for (int h = 0; h < 2; ++h) {
                const float4 xv = *reinterpret_cast<const float4*>(xrow + ct + lc + h * 4);
                const float4 ev = *reinterpret_cast<const float4*>(drow + ct + lc + h * 4);
                const int cb = lc + h * 4;
                xs[cb + 0][lr] = xv.x; xs[cb + 1][lr] = xv.y;
                xs[cb + 2][lr] = xv.z; xs[cb + 3][lr] = xv.w;
                es[cb + 0][lr] = ev.x * rcA; es[cb + 1][lr] = ev.y * rcA;
                es[cb + 2][lr] = ev.z * rcA; es[cb + 3][lr] = ev.w * rcA;
            }
            __syncthreads();
            #pragma unroll
            for (int c = 0; c < 32; ++c) {
                const float4 xa = *reinterpret_cast<const float4*>(&xs[c][ty * 4]);
                const float4 eb = *reinterpret_cast<const float4*>(&es[c][tx * 4]);
                const float xr_[4] = {xa.x, xa.y, xa.z, xa.w};
                const float ec_[4] = {eb.x, eb.y, eb.z, eb.w};
                #pragma unroll
                for (int i = 0; i < 4; ++i)
                    #pragma unroll
                    for (int j = 0; j < 4; ++j)
                        acc[i][j] += xr_[i] * ec_[j];
            }
        }
        const float4 e4 = *reinterpret_cast<const float4*>(&en2[kt + tx * 4]);
        const float en_[4] = {e4.x, e4.y, e4.z, e4.w};
        #pragma unroll
        for (int i = 0; i < 4; ++i)
            #pragma unroll
            for (int j = 0; j < 4; ++j) {
                const float s = en_[j] - 2.0f * acc[i][j];
                if (s < bestv[i]) { bestv[i] = s; besti[i] = kt + tx * 4 + j; }
            }
    }
    #pragma unroll
    for (int i = 0; i < 4; ++i) {
        red_v[ty * 4 + i][tx] = bestv[i];
        red_i[ty * 4 + i][tx] = besti[i];
    }
    __syncthreads();
    if (t < 64) {
        float bv = red_v[t][0]; int bi = red_i[t][0];
        #pragma unroll
        for (int c = 1; c < 16; ++c) {
            const float v = red_v[t][c]; const int idx = red_i[t][c];
            if (v < bv || (v == bv && idx < bi)) { bv = v; bi = idx; }
        }
        ids_sh[t] = bi;
        atomicAdd(&new_counts[bi], 1.0f);
    }
    __syncthreads();
    float lsum = 0.0f;
    for (int r = 0; r < 64; ++r) {
        const int id = ids_sh[r];
        const float rc = rcnt[id];
        const float* dr = dict + (size_t)id * C_DIM;
        const float* xr = x + (size_t)(m0 + r) * C_DIM;
        float* oq = out_xq + (size_t)(m0 + r) * C_DIM;
        float* nd = new_dict + (size_t)id * C_DIM;
        #pragma unroll
        for (int h = 0; h < 2; ++h) {
            const int c = t + h * 256;
            const float e  = dr[c] * rc;
            const float xv = xr[c];
            oq[c] = e;
            const float df = e - xv;
            lsum += df * df;
            atomicAdd(&nd[c], xv);
        }
    }
    #pragma unroll
    for (int off = 32; off > 0; off >>= 1) lsum += __shfl_down(lsum, off);
    if ((t & 63) == 0) lred[t >> 6] = lsum;
    __syncthreads();
    if (t == 0) loss_partials[blockIdx.x] = lred[0] + lred[1] + lred[2] + lred[3];
}

// ---------------- finalize: loss, perplexity -------------------------------
__global__ __launch_bounds__(256) void vq_finalize(const float* __restrict__ loss_partials,
                                                   const float* __restrict__ new_counts,
                                                   float* __restrict__ out_loss,
                                                   float* __restrict__ out_perp,
                                                   int n_partials) {
    const int t = threadIdx.x;
    __shared__ double red[256];
    __shared__ double total_sh;

    double ls = 0.0;
    for (int i = t; i < n_partials; i += 256) ls += (double)loss_partials[i];
    red[t] = ls; __syncthreads();
    for (int off = 128; off > 0; off >>= 1) {
        if (t < off) red[t] += red[t + off];
        __syncthreads();
    }
    if (t == 0) *out_loss = (float)((double)BETA * red[0] / ((double)M_TOTAL * (double)C_DIM));
    __syncthreads();

    double cs = 0.0;
    for (int i = t; i < K_VOCAB; i += 256) cs += (double)new_counts[i];
    red[t] = cs; __syncthreads();
    for (int off = 128; off > 0; off >>= 1) {
        if (t < off) red[t] += red[t + off];
        __syncthreads();
    }
    if (t == 0) total_sh = red[0];
    __syncthreads();
    const float total = (float)total_sh;

    double es = 0.0;
    for (int i = t; i < K_VOCAB; i += 256) {
        const float p = new_counts[i] / total;
        es += (double)(p * logf(p + 1e-10f));
    }
    red[t] = es; __syncthreads();
    for (int off = 128; off > 0; off >>= 1) {
        if (t < off) red[t] += red[t + off];
        __syncthreads();
    }
    if (t == 0) *out_perp = (float)exp(-red[0]);
}

extern "C" void kernel_launch(void* const* d_in, const int* in_sizes, int n_in,
                              void* d_out, int out_size, void* d_ws, size_t ws_size,
                              hipStream_t stream) {
    const float* x      = (const float*)d_in[0];
    const float* dict   = (const float*)d_in[1];
    const float* counts = (const float*)d_in[2];

    float* out        = (float*)d_out;
    float* out_xq     = out;
    float* out_loss   = out + (size_t)M_TOTAL * C_DIM;
    float* out_perp   = out_loss + 1;
    float* new_dict   = out_perp + 1;
    float* new_counts = new_dict + (size_t)K_VOCAB * C_DIM;

    float* ws       = (float*)d_ws;
    float* en2      = ws;                         // 8192
    float* rcnt     = ws + K_VOCAB;               // 8192
    float* partials = ws + 2 * K_VOCAB;           // 1024

    u64* part_keys = (u64*)(ws + 17408);          // byte 69632; 64K u64 = 512KB
    const size_t X2_off_f = 17408 + 131072;       // 148480 floats (16B aligned)
    const size_t X2_elems = (size_t)M_TOTAL * CK;
    const size_t E2_elems = (size_t)K_VOCAB * CK;
    const size_t need = X2_off_f * 4 + (X2_elems + E2_elems) * 2;

    if (ws_size >= need) {
        u16* X2 = (u16*)(ws + X2_off_f);
        u16* E2 = X2 + X2_elems;
        vq_prep_all<<<K_VOCAB + 2048, 256, 0, stream>>>(dict, counts, en2, rcnt,
                                                        new_dict, new_counts, E2, x, X2);
        vq_gemm8<<<256, 512, 0, stream>>>(X2, E2, en2, part_keys);
        vq_epi<<<1024, 256, 0, stream>>>(part_keys, x, dict, rcnt, out_xq,
                                         new_dict, new_counts, partials);
        vq_finalize<<<1, 256, 0, stream>>>(partials, new_counts, out_loss, out_perp, 1024);
    } else {
        vq_prep<<<K_VOCAB, 256, 0, stream>>>(dict, counts, en2, rcnt, new_dict, new_counts);
        vq_main<<<M_TOTAL / 64, 256, 0, stream>>>(x, dict, en2, rcnt, out_xq,
                                                  new_dict, new_counts, partials);
        vq_finalize<<<1, 256, 0, stream>>>(partials, new_counts, out_loss, out_perp, 512);
    }
}